// Round 2
// baseline (246.948 us; speedup 1.0000x reference)
//
#include <hip/hip_runtime.h>
#include <cstdint>
#include <cstddef>

// ---------------------------------------------------------------------------
// ChannelWiseCrossAttention: B=4, C=64, H=W=64, N=4096
//   q = log2e*(Wq x1 + bq)  [b][n][c] bf16      (log2e folded in for exp2)
//   k = Wk x2 + bk          [b][n][c] bf16
//   v = Wv x2 + bv          [b][c][n] bf16
//   S^T = K Q^T per 16-row tile (mfma 16x16x32 bf16, C/D: row=j, col=i)
//   p = exp2(S' - SHIFT)  (fixed shift, no max tracking; l summed per-lane)
//   O^T = V P^T  via 16x16x16 mfma: P^T's B-frag == S^T's C/D regs (!)
//   out = gamma*O/l + x1
// ---------------------------------------------------------------------------

typedef __bf16 bf16x4 __attribute__((ext_vector_type(4)));
typedef __bf16 bf16x8 __attribute__((ext_vector_type(8)));
typedef float  f32x4  __attribute__((ext_vector_type(4)));

constexpr int C = 64;
constexpr int N = 4096;
constexpr float LOG2E = 1.44269504088896340736f;
constexpr float EXPSHIFT = 48.0f * 1.44269504088896340736f; // ln-domain 48

static __device__ __forceinline__ f32x4 mfma_x32(bf16x8 a, bf16x8 b, f32x4 c) {
    return __builtin_amdgcn_mfma_f32_16x16x32_bf16(a, b, c, 0, 0, 0);
}

// 16x16x16 bf16 MFMA: prefer the native builtin; otherwise emulate with a
// zero-padded 16x16x32 (logical k16 = qd*4+t placed at k32 = qd*8+t in BOTH
// operands -> identical contraction).
static __device__ __forceinline__ f32x4 pv_mfma(bf16x4 a, bf16x4 b, f32x4 c) {
#if __has_builtin(__builtin_amdgcn_mfma_f32_16x16x16bf16_1k)
    typedef short v4s __attribute__((ext_vector_type(4)));
    union U { bf16x4 h; v4s s; };
    U ua; ua.h = a;
    U ub; ub.h = b;
    return __builtin_amdgcn_mfma_f32_16x16x16bf16_1k(ua.s, ub.s, c, 0, 0, 0);
#else
    const __bf16 z = (__bf16)0.0f;
    bf16x8 a8 = {a[0], a[1], a[2], a[3], z, z, z, z};
    bf16x8 b8 = {b[0], b[1], b[2], b[3], z, z, z, z};
    return __builtin_amdgcn_mfma_f32_16x16x32_bf16(a8, b8, c, 0, 0, 0);
#endif
}

static __device__ __forceinline__ float fast_exp2(float x) {
#if __has_builtin(__builtin_amdgcn_exp2f)
    return __builtin_amdgcn_exp2f(x);
#else
    return exp2f(x);
#endif
}

// ---------------------------------------------------------------------------
// Fused QKV 1x1-conv via MFMA. grid = B*(N/64) = 256 blocks, 256 threads.
// Per block: batch b, 64 pixels. Stage x1,x2 (transposed+direct) and all 3
// weights as bf16 in LDS, then 96 mfma_x32.
//   q,k: D[n][o] = X^T W^T : A[m=n][k=c]=x_t, B[k=c][n'=o]=W row-major
//   v  : D[o][n] = W X     : A[m=o][k=c]=Wv,  B[k=c][n]=x2 direct
// ---------------------------------------------------------------------------
__global__ __launch_bounds__(256) void qkv_kernel(
    const float* __restrict__ x1, const float* __restrict__ x2,
    const float* __restrict__ wq, const float* __restrict__ bq,
    const float* __restrict__ wk, const float* __restrict__ bk,
    const float* __restrict__ wv, const float* __restrict__ bv,
    __bf16* __restrict__ qo, __bf16* __restrict__ ko, __bf16* __restrict__ vo)
{
    __shared__ __bf16 wql[64][72], wkl[64][72], wvl[64][72];
    __shared__ __bf16 x1t[64][72], x2t[64][72];   // [n][c]
    __shared__ __bf16 x2c[64][74];                // [c][n], pad 74: 2-way max

    const int tid   = threadIdx.x;
    const int b     = blockIdx.x >> 6;
    const int nbase = (blockIdx.x & 63) * 64;

    // ---- stage ----
    {
        const int row = tid >> 2;              // W row / x channel
        const int c4  = (tid & 3) * 16;        // col base (16 elems/thread)
        const float* xr1 = x1 + ((size_t)b * C + row) * N + nbase + c4;
        const float* xr2 = x2 + ((size_t)b * C + row) * N + nbase + c4;
#pragma unroll
        for (int i = 0; i < 4; ++i) {
            float4 a;
            a = *(const float4*)(wq + row * 64 + c4 + i * 4);
            { bf16x4 h = {(__bf16)a.x,(__bf16)a.y,(__bf16)a.z,(__bf16)a.w};
              *(bf16x4*)&wql[row][c4 + i * 4] = h; }
            a = *(const float4*)(wk + row * 64 + c4 + i * 4);
            { bf16x4 h = {(__bf16)a.x,(__bf16)a.y,(__bf16)a.z,(__bf16)a.w};
              *(bf16x4*)&wkl[row][c4 + i * 4] = h; }
            a = *(const float4*)(wv + row * 64 + c4 + i * 4);
            { bf16x4 h = {(__bf16)a.x,(__bf16)a.y,(__bf16)a.z,(__bf16)a.w};
              *(bf16x4*)&wvl[row][c4 + i * 4] = h; }
            a = *(const float4*)(xr1 + i * 4);
            x1t[c4 + i * 4 + 0][row] = (__bf16)a.x;
            x1t[c4 + i * 4 + 1][row] = (__bf16)a.y;
            x1t[c4 + i * 4 + 2][row] = (__bf16)a.z;
            x1t[c4 + i * 4 + 3][row] = (__bf16)a.w;
            a = *(const float4*)(xr2 + i * 4);
            x2t[c4 + i * 4 + 0][row] = (__bf16)a.x;
            x2t[c4 + i * 4 + 1][row] = (__bf16)a.y;
            x2t[c4 + i * 4 + 2][row] = (__bf16)a.z;
            x2t[c4 + i * 4 + 3][row] = (__bf16)a.w;
            x2c[row][c4 + i * 4 + 0] = (__bf16)a.x;
            x2c[row][c4 + i * 4 + 1] = (__bf16)a.y;
            x2c[row][c4 + i * 4 + 2] = (__bf16)a.z;
            x2c[row][c4 + i * 4 + 3] = (__bf16)a.w;
        }
    }
    __syncthreads();

    // ---- compute ----
    const int wave = tid >> 6, lane = tid & 63;
    const int l = lane & 15, qd = lane >> 4;
    const int nt = wave;                       // each wave: 16 pixels

    bf16x8 ax1[2], ax2[2];
#pragma unroll
    for (int ks = 0; ks < 2; ++ks) {
        ax1[ks] = *(const bf16x8*)&x1t[nt * 16 + l][ks * 32 + qd * 8];
        ax2[ks] = *(const bf16x8*)&x2t[nt * 16 + l][ks * 32 + qd * 8];
    }

    // q, k: D[n][o]
    const size_t qkbase = ((size_t)b * N + nbase + nt * 16) * C;
#pragma unroll
    for (int ot = 0; ot < 4; ++ot) {
        const float bqv = bq[ot * 16 + l];
        const float bkv = bk[ot * 16 + l];
        f32x4 aq = {bqv, bqv, bqv, bqv};
        f32x4 akk = {bkv, bkv, bkv, bkv};
#pragma unroll
        for (int ks = 0; ks < 2; ++ks) {
            bf16x8 bwq = *(const bf16x8*)&wql[ot * 16 + l][ks * 32 + qd * 8];
            bf16x8 bwk = *(const bf16x8*)&wkl[ot * 16 + l][ks * 32 + qd * 8];
            aq  = mfma_x32(ax1[ks], bwq, aq);
            akk = mfma_x32(ax2[ks], bwk, akk);
        }
#pragma unroll
        for (int r = 0; r < 4; ++r) {
            qo[qkbase + (size_t)(qd * 4 + r) * C + ot * 16 + l] = (__bf16)(aq[r] * LOG2E);
            ko[qkbase + (size_t)(qd * 4 + r) * C + ot * 16 + l] = (__bf16)akk[r];
        }
    }

    // v: D[o][n]
    bf16x8 bx2[2];
#pragma unroll
    for (int ks = 0; ks < 2; ++ks) {
        bf16x8 t;
#pragma unroll
        for (int t8 = 0; t8 < 8; ++t8)
            t[t8] = x2c[ks * 32 + qd * 8 + t8][nt * 16 + l];
        bx2[ks] = t;
    }
#pragma unroll
    for (int ct = 0; ct < 4; ++ct) {
        f32x4 avv;
#pragma unroll
        for (int r = 0; r < 4; ++r) avv[r] = bv[ct * 16 + qd * 4 + r];
#pragma unroll
        for (int ks = 0; ks < 2; ++ks) {
            bf16x8 awv = *(const bf16x8*)&wvl[ct * 16 + l][ks * 32 + qd * 8];
            avv = mfma_x32(awv, bx2[ks], avv);
        }
#pragma unroll
        for (int r = 0; r < 4; ++r)
            vo[((size_t)b * C + ct * 16 + qd * 4 + r) * N + nbase + nt * 16 + l] = (__bf16)avv[r];
    }
}

// ---------------------------------------------------------------------------
// Attention, register-resident P. grid = 256 blocks x 4 waves, 16 rows/wave.
// Per 64-j tile: 8 mfma (S^T) + 16 exp2 + 16 mfma (PV). No LDS, no shuffles
// in the loop. K/V fragments double-buffered.
// ---------------------------------------------------------------------------
__global__ __launch_bounds__(256, 1) void attn_kernel(
    const __bf16* __restrict__ qg, const __bf16* __restrict__ kg,
    const __bf16* __restrict__ vg, const float* __restrict__ x1,
    const float* __restrict__ gamma, float* __restrict__ out)
{
    const int tid  = threadIdx.x;
    const int wave = tid >> 6, lane = tid & 63;
    const int l = lane & 15, qd = lane >> 4;
    const int b     = blockIdx.x >> 6;
    const int ibase = (blockIdx.x & 63) * 64 + wave * 16;

    const __bf16* qb = qg + (size_t)b * N * C;   // [i][c]
    const __bf16* kb = kg + (size_t)b * N * C;   // [j][c]
    const __bf16* vb = vg + (size_t)b * C * N;   // [c][j]

    // Q B-frag (x32): B[k=c][n=i]
    bf16x8 bq0 = *(const bf16x8*)(qb + (size_t)(ibase + l) * C + qd * 8);
    bf16x8 bq1 = *(const bf16x8*)(qb + (size_t)(ibase + l) * C + 32 + qd * 8);

    f32x4 accO[4];
#pragma unroll
    for (int ct = 0; ct < 4; ++ct) accO[ct] = (f32x4){0.f, 0.f, 0.f, 0.f};
    float lsum = 0.f;

    bf16x8 ak[2][4][2];   // K A-frags (x32): [buf][jt][ks]
    bf16x4 av[2][4][4];   // V A-frags (x16): [buf][ct][js]

#define LOAD_TILE(JB, BUF)                                                          \
    do {                                                                            \
        _Pragma("unroll")                                                           \
        for (int jt = 0; jt < 4; ++jt)                                              \
            _Pragma("unroll")                                                       \
            for (int ks = 0; ks < 2; ++ks)                                          \
                ak[BUF][jt][ks] = *(const bf16x8*)(kb + (size_t)((JB) + jt * 16 + l) * C + ks * 32 + qd * 8); \
        _Pragma("unroll")                                                           \
        for (int ct = 0; ct < 4; ++ct)                                              \
            _Pragma("unroll")                                                       \
            for (int js = 0; js < 4; ++js)                                          \
                av[BUF][ct][js] = *(const bf16x4*)(vb + (size_t)(ct * 16 + l) * N + (JB) + js * 16 + qd * 4); \
    } while (0)

    LOAD_TILE(0, 0);

#pragma unroll 2
    for (int t = 0; t < 64; ++t) {
        const int cur = t & 1;
        if (t < 63) LOAD_TILE((t + 1) * 64, cur ^ 1);

        // S^T = K Q^T : rows j = qd*4+r (+jt*16), cols i = l
        f32x4 st[4];
#pragma unroll
        for (int jt = 0; jt < 4; ++jt) {
            st[jt] = mfma_x32(ak[cur][jt][0], bq0, (f32x4){0.f, 0.f, 0.f, 0.f});
            st[jt] = mfma_x32(ak[cur][jt][1], bq1, st[jt]);
        }

        // p = exp2(S' - SHIFT); C/D regs ARE the x16 B-frag (k=qd*4+r, n=l)
        bf16x4 bp[4];
#pragma unroll
        for (int jt = 0; jt < 4; ++jt)
#pragma unroll
            for (int r = 0; r < 4; ++r) {
                float p = fast_exp2(st[jt][r] - EXPSHIFT);
                lsum += p;
                bp[jt][r] = (__bf16)p;
            }

        // O^T += V P^T : rows c = qd*4+r (+ct*16), cols i = l
#pragma unroll
        for (int ct = 0; ct < 4; ++ct)
#pragma unroll
            for (int js = 0; js < 4; ++js)
                accO[ct] = pv_mfma(av[cur][ct][js], bp[js], accO[ct]);
    }
#undef LOAD_TILE

    // l: per-lane partial covers disjoint j; combine quads once.
    lsum += __shfl_xor(lsum, 16);
    lsum += __shfl_xor(lsum, 32);
    const float sc = gamma[0] / lsum;

#pragma unroll
    for (int ct = 0; ct < 4; ++ct)
#pragma unroll
        for (int r = 0; r < 4; ++r) {
            const size_t idx = ((size_t)b * C + ct * 16 + qd * 4 + r) * N + ibase + l;
            out[idx] = sc * accO[ct][r] + x1[idx];
        }
}

// ---------------------------------------------------------------------------
extern "C" void kernel_launch(void* const* d_in, const int* in_sizes, int n_in,
                              void* d_out, int out_size, void* d_ws, size_t ws_size,
                              hipStream_t stream) {
    const float* x1    = (const float*)d_in[0];
    const float* x2    = (const float*)d_in[1];
    const float* wq    = (const float*)d_in[2];
    const float* bqv   = (const float*)d_in[3];
    const float* wk    = (const float*)d_in[4];
    const float* bkv   = (const float*)d_in[5];
    const float* wv    = (const float*)d_in[6];
    const float* bvv   = (const float*)d_in[7];
    const float* gamma = (const float*)d_in[8];
    float* out = (float*)d_out;

    __bf16* qws = (__bf16*)d_ws;                   // [B][N][C] bf16, 2 MB
    __bf16* kws = qws + (size_t)4 * N * C;         // [B][N][C] bf16, 2 MB
    __bf16* vws = kws + (size_t)4 * N * C;         // [B][C][N] bf16, 2 MB

    qkv_kernel<<<256, 256, 0, stream>>>(x1, x2, wq, bqv, wk, bkv, wv, bvv, qws, kws, vws);
    attn_kernel<<<256, 256, 0, stream>>>(qws, kws, vws, x1, gamma, out);
}

// Round 3
// 167.665 us; speedup vs baseline: 1.4729x; 1.4729x over previous
//
#include <hip/hip_runtime.h>
#include <cstdint>
#include <cstddef>

// ---------------------------------------------------------------------------
// ChannelWiseCrossAttention: B=4, C=64, H=W=64, N=4096
//   q = log2e*(Wq x1 + bq)  [b][n][c] bf16
//   k = Wk x2 + bk          [b][n][c] bf16
//   v = Wv x2 + bv          [b][c][n] bf16
// attn kernel: 512 blocks x 8 waves; block = 32 Q-rows; wave = 1/8 of j.
//   S^T = K Q^T  (mfma_f32_32x32x16_bf16, C/D: row=j', col=i')
//   p = exp2(S - SHIFT); S^T C/D regs 4r..4r+3 ARE the B-frag of
//   mfma_f32_32x32x8_bf16 -> O^T += V P^T entirely in registers.
//   Partial (O,l) over disjoint j combine by addition via LDS tree.
// ---------------------------------------------------------------------------

typedef __bf16 bf16x4 __attribute__((ext_vector_type(4)));
typedef __bf16 bf16x8 __attribute__((ext_vector_type(8)));
typedef float  f32x4  __attribute__((ext_vector_type(4)));
typedef float  f32x16 __attribute__((ext_vector_type(16)));
typedef short  s16x4  __attribute__((ext_vector_type(4)));

constexpr int C = 64;
constexpr int N = 4096;
constexpr float LOG2E = 1.44269504088896340736f;
constexpr float EXPSHIFT = 48.0f * 1.44269504088896340736f;  // ln-domain 48

static __device__ __forceinline__ f32x4 mfma16(bf16x8 a, bf16x8 b, f32x4 c) {
    return __builtin_amdgcn_mfma_f32_16x16x32_bf16(a, b, c, 0, 0, 0);
}
static __device__ __forceinline__ f32x16 mfma32(bf16x8 a, bf16x8 b, f32x16 c) {
    return __builtin_amdgcn_mfma_f32_32x32x16_bf16(a, b, c, 0, 0, 0);
}
// 32x32x8 bf16: A/B = 4 bf16 (k = 4*(lane>>5)+j). Native if present, else
// zero-padded 32x32x16 (k8=4hi+j embedded at slot j in both operands).
static __device__ __forceinline__ f32x16 pv_mfma(bf16x4 a, bf16x4 b, f32x16 c) {
#if __has_builtin(__builtin_amdgcn_mfma_f32_32x32x8bf16_1k)
    union U { bf16x4 h; s16x4 s; };
    U ua; ua.h = a;
    U ub; ub.h = b;
    return __builtin_amdgcn_mfma_f32_32x32x8bf16_1k(ua.s, ub.s, c, 0, 0, 0);
#else
    const __bf16 z = (__bf16)0.0f;
    bf16x8 a8 = {a[0], a[1], a[2], a[3], z, z, z, z};
    bf16x8 b8 = {b[0], b[1], b[2], b[3], z, z, z, z};
    return __builtin_amdgcn_mfma_f32_32x32x16_bf16(a8, b8, c, 0, 0, 0);
#endif
}
static __device__ __forceinline__ float fast_exp2(float x) {
#if __has_builtin(__builtin_amdgcn_exp2f)
    return __builtin_amdgcn_exp2f(x);
#else
    return exp2f(x);
#endif
}

// ---------------------------------------------------------------------------
// QKV conv. grid = 256 blocks x 256 thr (4 waves x 16 pixels). Weights staged
// row-major bf16 in LDS (no transpose needed); x fragments loaded straight
// from global (each load inst = 4 x 64B coalesced segments); x2 frag shared
// between K (A-operand) and V (B-operand).
//   q,k: D[n][o] = X^T W^T : A[m=n][k=c] from x, B[k=c][n=o] = W row-major
//   v  : D[o][n] = W X     : A[m=o][k=c] = Wv row-major, B[k=c][n] from x2
// 16x16x32 layouts: A/B per-lane 8 elems k=(lane>>4)*8+j; C/D row=(lane>>4)*4+r.
// ---------------------------------------------------------------------------
__global__ __launch_bounds__(256) void qkv_kernel(
    const float* __restrict__ x1, const float* __restrict__ x2,
    const float* __restrict__ wq, const float* __restrict__ bq,
    const float* __restrict__ wk, const float* __restrict__ bk,
    const float* __restrict__ wv, const float* __restrict__ bv,
    __bf16* __restrict__ qo, __bf16* __restrict__ ko, __bf16* __restrict__ vo)
{
    __shared__ __bf16 wl[3][64][72];   // row-major, stride 144B (16B-aligned)

    const int tid   = threadIdx.x;
    const int b     = blockIdx.x >> 6;
    const int nbase = (blockIdx.x & 63) * 64;

    // stage weights: 3 x 1024 float4 chunks over 256 threads
    {
        const float* wp[3] = {wq, wk, wv};
#pragma unroll
        for (int m = 0; m < 3; ++m)
#pragma unroll
            for (int i = 0; i < 4; ++i) {
                int idx = i * 256 + tid;
                int row = idx >> 4, c4 = (idx & 15) * 4;
                float4 a = *(const float4*)(wp[m] + row * 64 + c4);
                bf16x4 h = {(__bf16)a.x, (__bf16)a.y, (__bf16)a.z, (__bf16)a.w};
                *(bf16x4*)&wl[m][row][c4] = h;
            }
    }
    __syncthreads();

    const int wave = tid >> 6, lane = tid & 63;
    const int l = lane & 15, qd = lane >> 4;
    const int p = nbase + wave * 16 + l;          // this lane's pixel (A/B col)

    // x fragments: A[m=p][k=c], c = ks*32 + qd*8 + j  (scalar dword loads,
    // 4x64B coalesced per instruction)
    const float* x1b = x1 + (size_t)b * C * N + p;
    const float* x2b = x2 + (size_t)b * C * N + p;
    bf16x8 ax1[2], ax2[2];
#pragma unroll
    for (int ks = 0; ks < 2; ++ks) {
#pragma unroll
        for (int j = 0; j < 8; ++j) {
            int c = ks * 32 + qd * 8 + j;
            ax1[ks][j] = (__bf16)x1b[(size_t)c * N];
            ax2[ks][j] = (__bf16)x2b[(size_t)c * N];
        }
    }

    // Q, K: D[n][o]
    const size_t qkrow = ((size_t)b * N + nbase + wave * 16) * C;
#pragma unroll
    for (int ot = 0; ot < 4; ++ot) {
        const float bqv = bq[ot * 16 + l];
        const float bkv = bk[ot * 16 + l];
        f32x4 aq = {bqv, bqv, bqv, bqv};
        f32x4 ak = {bkv, bkv, bkv, bkv};
#pragma unroll
        for (int ks = 0; ks < 2; ++ks) {
            bf16x8 bwq = *(const bf16x8*)&wl[0][ot * 16 + l][ks * 32 + qd * 8];
            bf16x8 bwk = *(const bf16x8*)&wl[1][ot * 16 + l][ks * 32 + qd * 8];
            aq = mfma16(ax1[ks], bwq, aq);
            ak = mfma16(ax2[ks], bwk, ak);
        }
#pragma unroll
        for (int r = 0; r < 4; ++r) {
            qo[qkrow + (size_t)(qd * 4 + r) * C + ot * 16 + l] = (__bf16)(aq[r] * LOG2E);
            ko[qkrow + (size_t)(qd * 4 + r) * C + ot * 16 + l] = (__bf16)ak[r];
        }
    }

    // V: D[o][n], B-operand = same registers as ax2
#pragma unroll
    for (int ct = 0; ct < 4; ++ct) {
        f32x4 av;
#pragma unroll
        for (int r = 0; r < 4; ++r) av[r] = bv[ct * 16 + qd * 4 + r];
#pragma unroll
        for (int ks = 0; ks < 2; ++ks) {
            bf16x8 awv = *(const bf16x8*)&wl[2][ct * 16 + l][ks * 32 + qd * 8];
            av = mfma16(awv, ax2[ks], av);
        }
#pragma unroll
        for (int r = 0; r < 4; ++r)
            vo[((size_t)b * C + ct * 16 + qd * 4 + r) * N + p] = (__bf16)av[r];
    }
}

// ---------------------------------------------------------------------------
// Attention. grid = 512 blocks x 512 thr. Block = (b, 32-row Q-tile); wave w
// owns j in [w*512, w*512+512) as 16 tiles of 32. XCD swizzle: batch per
// XCD pair so each XCD's L2 holds one batch's K/V (1 MB).
// 32x32x16 layouts: A/B per-lane 8 elems k=(lane>>5)*8+j;
//                   C/D 16 regs: row=(r&3)+8*(r>>2)+4*(lane>>5), col=lane&31.
// ---------------------------------------------------------------------------
__global__ __launch_bounds__(512, 4) void attn_kernel(
    const __bf16* __restrict__ qg, const __bf16* __restrict__ kg,
    const __bf16* __restrict__ vg, const float* __restrict__ x1,
    const float* __restrict__ gamma, float* __restrict__ out)
{
    __shared__ float lds_acc[7][64][32];   // 7 combine slots, 56 KB
    __shared__ float lds_l[7][32];

    const int bid = blockIdx.x;
    const int xcd = bid & 7;
    const int b   = xcd >> 1;
    const int rt  = ((bid >> 3) << 1) | (xcd & 1);   // 0..127
    const int ibase = rt * 32;

    const int tid  = threadIdx.x;
    const int wave = tid >> 6, lane = tid & 63;
    const int il = lane & 31, hi = lane >> 5;

    const __bf16* qb = qg + (size_t)b * N * C;   // [i][c]
    const __bf16* kb = kg + (size_t)b * N * C;   // [j][c]
    const __bf16* vb = vg + (size_t)b * C * N;   // [c][j]

    // Q B-frags: B[k=c][n=i], 4 c-chunks of 16
    bf16x8 bqf[4];
#pragma unroll
    for (int kc = 0; kc < 4; ++kc)
        bqf[kc] = *(const bf16x8*)(qb + (size_t)(ibase + il) * C + kc * 16 + hi * 8);

    f32x16 accO[2];
#pragma unroll
    for (int ct = 0; ct < 2; ++ct)
#pragma unroll
        for (int r = 0; r < 16; ++r) accO[ct][r] = 0.f;
    float lsum = 0.f;

    const int jstart = wave * 512;
#pragma unroll 2
    for (int t = 0; t < 16; ++t) {
        const int jb = jstart + t * 32;

        // K A-frags: A[m=j][k=c]
        bf16x8 akf[4];
#pragma unroll
        for (int kc = 0; kc < 4; ++kc)
            akf[kc] = *(const bf16x8*)(kb + (size_t)(jb + il) * C + kc * 16 + hi * 8);

        // V A-frags (32x32x8): A[m=c][k=j], j = jb + kcs*8 + hi*4 + j'
        bf16x4 avf[2][4];
#pragma unroll
        for (int ct = 0; ct < 2; ++ct)
#pragma unroll
            for (int kcs = 0; kcs < 4; ++kcs)
                avf[ct][kcs] = *(const bf16x4*)(vb + (size_t)(ct * 32 + il) * N + jb + kcs * 8 + hi * 4);

        // S^T = K Q^T
        f32x16 st;
#pragma unroll
        for (int r = 0; r < 16; ++r) st[r] = 0.f;
#pragma unroll
        for (int kc = 0; kc < 4; ++kc) st = mfma32(akf[kc], bqf[kc], st);

        // p = exp2(S - SHIFT); regs 4k..4k+3 = B-frag of PV mfma k-chunk k
        bf16x4 bp[4];
#pragma unroll
        for (int r = 0; r < 16; ++r) {
            float pv = fast_exp2(st[r] - EXPSHIFT);
            lsum += pv;
            bp[r >> 2][r & 3] = (__bf16)pv;
        }

        // O^T += V P^T
#pragma unroll
        for (int ct = 0; ct < 2; ++ct)
#pragma unroll
            for (int kcs = 0; kcs < 4; ++kcs)
                accO[ct] = pv_mfma(avf[ct][kcs], bp[kcs], accO[ct]);
    }

    // per-lane lsum -> per-column(i) sum within wave
    lsum += __shfl_xor(lsum, 32);

    // ---- cross-wave combine (tree through 7 LDS slots) ----
    // accO lane element (ct,r) -> c = ct*32 + (r&3)+8*(r>>2)+4*hi, i = il
#define ACC_STORE(SLOT)                                                        \
    do {                                                                       \
        _Pragma("unroll")                                                      \
        for (int ct = 0; ct < 2; ++ct)                                         \
            _Pragma("unroll")                                                  \
            for (int r = 0; r < 16; ++r)                                       \
                lds_acc[SLOT][ct * 32 + (r & 3) + 8 * (r >> 2) + 4 * hi][il] = accO[ct][r]; \
        if (hi == 0) lds_l[SLOT][il] = lsum;                                   \
    } while (0)
#define ACC_LOAD(SLOT)                                                         \
    do {                                                                       \
        _Pragma("unroll")                                                      \
        for (int ct = 0; ct < 2; ++ct)                                         \
            _Pragma("unroll")                                                  \
            for (int r = 0; r < 16; ++r)                                       \
                accO[ct][r] += lds_acc[SLOT][ct * 32 + (r & 3) + 8 * (r >> 2) + 4 * hi][il]; \
        lsum += lds_l[SLOT][il];                                               \
    } while (0)

    if (wave >= 4) ACC_STORE(wave - 1);          // slots 3..6
    __syncthreads();
    if (wave < 4) {
        ACC_LOAD(wave + 3);
        if (wave >= 1) ACC_STORE(wave - 1);      // slots 0..2
    }
    __syncthreads();
    if (wave == 0) {
        ACC_LOAD(0); ACC_LOAD(1); ACC_LOAD(2);
        ACC_STORE(0);                            // totals -> slot 0
    }
    __syncthreads();
#undef ACC_STORE
#undef ACC_LOAD

    // ---- parallel epilogue: out = gamma*O/l + x1 ----
    const float g = gamma[0];
    {
        const int c  = tid >> 3;          // 0..63
        const int i4 = (tid & 7) * 4;     // 0..28
        f32x4 o  = *(const f32x4*)&lds_acc[0][c][i4];
        f32x4 lt = *(const f32x4*)&lds_l[0][i4];
        const size_t idx = ((size_t)b * C + c) * N + ibase + i4;
        f32x4 xv = *(const f32x4*)(x1 + idx);
        f32x4 res;
#pragma unroll
        for (int e = 0; e < 4; ++e) res[e] = g * o[e] / lt[e] + xv[e];
        *(f32x4*)(out + idx) = res;
    }
}

// ---------------------------------------------------------------------------
extern "C" void kernel_launch(void* const* d_in, const int* in_sizes, int n_in,
                              void* d_out, int out_size, void* d_ws, size_t ws_size,
                              hipStream_t stream) {
    const float* x1    = (const float*)d_in[0];
    const float* x2    = (const float*)d_in[1];
    const float* wq    = (const float*)d_in[2];
    const float* bqv   = (const float*)d_in[3];
    const float* wk    = (const float*)d_in[4];
    const float* bkv   = (const float*)d_in[5];
    const float* wv    = (const float*)d_in[6];
    const float* bvv   = (const float*)d_in[7];
    const float* gamma = (const float*)d_in[8];
    float* out = (float*)d_out;

    __bf16* qws = (__bf16*)d_ws;                   // [B][N][C] bf16, 2 MB
    __bf16* kws = qws + (size_t)4 * N * C;         // [B][N][C] bf16, 2 MB
    __bf16* vws = kws + (size_t)4 * N * C;         // [B][C][N] bf16, 2 MB

    qkv_kernel<<<256, 256, 0, stream>>>(x1, x2, wq, bqv, wk, bkv, wv, bvv, qws, kws, vws);
    attn_kernel<<<512, 512, 0, stream>>>(qws, kws, vws, x1, gamma, out);
}

// Round 4
// 107.769 us; speedup vs baseline: 2.2915x; 1.5558x over previous
//
#include <hip/hip_runtime.h>
#include <cstdint>
#include <cstddef>

// ---------------------------------------------------------------------------
// ChannelWiseCrossAttention: B=4, C=64, H=W=64, N=4096
// Workspace layouts are MFMA-fragment-major so every attn load instruction is
// wave-contiguous:
//   Q,K per (b, 32-row tile jt): [kc(4)][hi(2)][il(32)][e(8)]  (2048 elems)
//     element (row il, c = kc*16+hi*8+e)
//   V  per (b, 32-col tile jt): [kcs(4)][hi(2)][c(64)][e(4)]   (2048 elems)
//     element (c, j = kcs*8+hi*4+e)
// attn: 512 blocks x 8 waves; block = 32 Q-rows; wave = 1/8 of j (16 tiles).
//   S^T = K Q^T (mfma_f32_32x32x16_bf16), p = exp2(S' - SHIFT) in-register,
//   O^T += V P^T (mfma 32x32x8, S^T C/D regs 4g..4g+3 are the B-frag).
//   Partial (O,l) combine via 4-slot LDS tree.
// ---------------------------------------------------------------------------

typedef __bf16 bf16x4 __attribute__((ext_vector_type(4)));
typedef __bf16 bf16x8 __attribute__((ext_vector_type(8)));
typedef float  f32x4  __attribute__((ext_vector_type(4)));
typedef float  f32x16 __attribute__((ext_vector_type(16)));
typedef short  s16x4  __attribute__((ext_vector_type(4)));

constexpr int C = 64;
constexpr int N = 4096;
constexpr float LOG2E = 1.44269504088896340736f;
constexpr float EXPSHIFT = 48.0f * 1.44269504088896340736f;  // ln-domain 48

static __device__ __forceinline__ f32x4 mfma16(bf16x8 a, bf16x8 b, f32x4 c) {
    return __builtin_amdgcn_mfma_f32_16x16x32_bf16(a, b, c, 0, 0, 0);
}
static __device__ __forceinline__ f32x16 mfma32(bf16x8 a, bf16x8 b, f32x16 c) {
    return __builtin_amdgcn_mfma_f32_32x32x16_bf16(a, b, c, 0, 0, 0);
}
// 32x32x8 bf16 (A/B = 4 bf16, k = 4*hi + j). Native if available, else
// zero-padded 32x32x16 (logical k at slot j in both operands).
static __device__ __forceinline__ f32x16 pv_mfma(bf16x4 a, bf16x4 b, f32x16 c) {
#if __has_builtin(__builtin_amdgcn_mfma_f32_32x32x8bf16_1k)
    union U { bf16x4 h; s16x4 s; };
    U ua; ua.h = a;
    U ub; ub.h = b;
    return __builtin_amdgcn_mfma_f32_32x32x8bf16_1k(ua.s, ub.s, c, 0, 0, 0);
#else
    const __bf16 z = (__bf16)0.0f;
    bf16x8 a8 = {a[0], a[1], a[2], a[3], z, z, z, z};
    bf16x8 b8 = {b[0], b[1], b[2], b[3], z, z, z, z};
    return __builtin_amdgcn_mfma_f32_32x32x16_bf16(a8, b8, c, 0, 0, 0);
#endif
}
static __device__ __forceinline__ float fast_exp2(float x) {
#if __has_builtin(__builtin_amdgcn_exp2f)
    return __builtin_amdgcn_exp2f(x);
#else
    return exp2f(x);
#endif
}

// ---------------------------------------------------------------------------
// QKV conv. grid = 256 blocks x 256 thr (4 waves x 16 pixels). Weights staged
// row-major bf16 in LDS; x fragments loaded straight from global.
//   q,k: D[n][o] = X^T W^T ; v: D[o][n] = W X  (16x16x32 MFMAs)
// Outputs written in the fragment-major tiled layouts above.
// ---------------------------------------------------------------------------
__global__ __launch_bounds__(256) void qkv_kernel(
    const float* __restrict__ x1, const float* __restrict__ x2,
    const float* __restrict__ wq, const float* __restrict__ bq,
    const float* __restrict__ wk, const float* __restrict__ bk,
    const float* __restrict__ wv, const float* __restrict__ bv,
    __bf16* __restrict__ qo, __bf16* __restrict__ ko, __bf16* __restrict__ vo)
{
    __shared__ __bf16 wl[3][64][72];

    const int tid   = threadIdx.x;
    const int b     = blockIdx.x >> 6;
    const int nbase = (blockIdx.x & 63) * 64;

    {
        const float* wp[3] = {wq, wk, wv};
#pragma unroll
        for (int m = 0; m < 3; ++m)
#pragma unroll
            for (int i = 0; i < 4; ++i) {
                int idx = i * 256 + tid;
                int row = idx >> 4, c4 = (idx & 15) * 4;
                float4 a = *(const float4*)(wp[m] + row * 64 + c4);
                bf16x4 h = {(__bf16)a.x, (__bf16)a.y, (__bf16)a.z, (__bf16)a.w};
                *(bf16x4*)&wl[m][row][c4] = h;
            }
    }
    __syncthreads();

    const int wave = tid >> 6, lane = tid & 63;
    const int l = lane & 15, qd = lane >> 4;
    const int p = nbase + wave * 16 + l;          // pixel (A col)

    const float* x1b = x1 + (size_t)b * C * N + p;
    const float* x2b = x2 + (size_t)b * C * N + p;
    bf16x8 ax1[2], ax2[2];
#pragma unroll
    for (int ks = 0; ks < 2; ++ks)
#pragma unroll
        for (int j = 0; j < 8; ++j) {
            int c = ks * 32 + qd * 8 + j;
            ax1[ks][j] = (__bf16)x1b[(size_t)c * N];
            ax2[ks][j] = (__bf16)x2b[(size_t)c * N];
        }

    // tile base for this wave's 16 pixels (32-row tile index)
    const size_t tb = ((size_t)b * 128 + (nbase >> 5) + (wave >> 1)) * 2048;

    // Q, K: D[n][o]; thread (l,qd) holds d[row p32 = (wave&1)*16+qd*4+r][o=ot*16+l]
#pragma unroll
    for (int ot = 0; ot < 4; ++ot) {
        const float bqv = bq[ot * 16 + l];
        const float bkv = bk[ot * 16 + l];
        f32x4 aq = {bqv, bqv, bqv, bqv};
        f32x4 ak = {bkv, bkv, bkv, bkv};
#pragma unroll
        for (int ks = 0; ks < 2; ++ks) {
            bf16x8 bwq = *(const bf16x8*)&wl[0][ot * 16 + l][ks * 32 + qd * 8];
            bf16x8 bwk = *(const bf16x8*)&wl[1][ot * 16 + l][ks * 32 + qd * 8];
            aq = mfma16(ax1[ks], bwq, aq);
            ak = mfma16(ax2[ks], bwk, ak);
        }
#pragma unroll
        for (int r = 0; r < 4; ++r) {
            int p32 = (wave & 1) * 16 + qd * 4 + r;
            size_t idx = tb + ot * 512 + (l >> 3) * 256 + p32 * 8 + (l & 7);
            qo[idx] = (__bf16)(aq[r] * LOG2E);
            ko[idx] = (__bf16)ak[r];
        }
    }

    // V: D[o][n]; thread holds d[o = ct*16+qd*4+r][pixel p]
    const int kcs = ((wave & 1) * 16 + l) >> 3;
    const int vhi = (l >> 2) & 1;
#pragma unroll
    for (int ct = 0; ct < 4; ++ct) {
        f32x4 av;
#pragma unroll
        for (int r = 0; r < 4; ++r) av[r] = bv[ct * 16 + qd * 4 + r];
#pragma unroll
        for (int ks = 0; ks < 2; ++ks) {
            bf16x8 awv = *(const bf16x8*)&wl[2][ct * 16 + l][ks * 32 + qd * 8];
            av = mfma16(awv, ax2[ks], av);
        }
#pragma unroll
        for (int r = 0; r < 4; ++r) {
            int o = ct * 16 + qd * 4 + r;
            vo[tb + kcs * 512 + vhi * 256 + o * 4 + (l & 3)] = (__bf16)av[r];
        }
    }
}

// ---------------------------------------------------------------------------
// Attention. grid = 512 blocks x 512 thr. Block = (b, 32-row Q-tile); wave w
// owns j-tiles [w*16, w*16+16). All loads wave-contiguous (frag-major layout).
// 32x32x16: A/B 8 elems k=(lane>>5)*8+j; C/D row=(r&3)+8*(r>>2)+4*hi, col=il.
// ---------------------------------------------------------------------------
__global__ __launch_bounds__(512, 4) void attn_kernel(
    const __bf16* __restrict__ qg, const __bf16* __restrict__ kg,
    const __bf16* __restrict__ vg, const float* __restrict__ x1,
    const float* __restrict__ gamma, float* __restrict__ out)
{
    __shared__ float lds_acc[4][64][32];   // 4 combine slots, 32 KB
    __shared__ float lds_l[4][32];

    const int bid = blockIdx.x;
    const int xcd = bid & 7;
    const int b   = xcd >> 1;
    const int rt  = ((bid >> 3) << 1) | (xcd & 1);   // 0..127
    const int ibase = rt * 32;

    const int tid  = threadIdx.x;
    const int wave = tid >> 6, lane = tid & 63;
    const int il = lane & 31, hi = lane >> 5;

    const __bf16* qt = qg + ((size_t)b * 128 + rt) * 2048;
    const __bf16* kt = kg + (size_t)b * 128 * 2048 + (size_t)(wave * 16) * 2048;
    const __bf16* vt = vg + (size_t)b * 128 * 2048 + (size_t)(wave * 16) * 2048;

    // Q B-frags: 1 KB contiguous per load
    bf16x8 bqf[4];
#pragma unroll
    for (int kc = 0; kc < 4; ++kc)
        bqf[kc] = *(const bf16x8*)(qt + kc * 512 + lane * 8);

    f32x16 accO[2];
#pragma unroll
    for (int ct = 0; ct < 2; ++ct)
#pragma unroll
        for (int r = 0; r < 16; ++r) accO[ct][r] = 0.f;
    float lsum = 0.f;

    bf16x8 akf[2][4];   // K frags, double-buffered
    bf16x4 avf[2][4];   // V frags [ct][kcs], single buffer (used late in body)

#pragma unroll
    for (int kc = 0; kc < 4; ++kc)
        akf[0][kc] = *(const bf16x8*)(kt + kc * 512 + lane * 8);

#pragma unroll
    for (int t = 0; t < 16; ++t) {
        const int cur = t & 1;
        if (t < 15) {
#pragma unroll
            for (int kc = 0; kc < 4; ++kc)
                akf[cur ^ 1][kc] = *(const bf16x8*)(kt + (size_t)(t + 1) * 2048 + kc * 512 + lane * 8);
        }
        // V for current tile (needed only after S^T + exp)
#pragma unroll
        for (int ct = 0; ct < 2; ++ct)
#pragma unroll
            for (int kcs = 0; kcs < 4; ++kcs)
                avf[ct][kcs] = *(const bf16x4*)(vt + (size_t)t * 2048 + kcs * 512 + hi * 256 + ct * 128 + il * 4);

        // S^T = K Q^T
        f32x16 st;
#pragma unroll
        for (int r = 0; r < 16; ++r) st[r] = 0.f;
#pragma unroll
        for (int kc = 0; kc < 4; ++kc) st = mfma32(akf[cur][kc], bqf[kc], st);

        // p = exp2(S' - SHIFT); regs 4g..4g+3 = B-frag of PV k-chunk g
        bf16x4 bp[4];
#pragma unroll
        for (int r = 0; r < 16; ++r) {
            float pv = fast_exp2(st[r] - EXPSHIFT);
            lsum += pv;
            bp[r >> 2][r & 3] = (__bf16)pv;
        }

        // O^T += V P^T
#pragma unroll
        for (int ct = 0; ct < 2; ++ct)
#pragma unroll
            for (int kcs = 0; kcs < 4; ++kcs)
                accO[ct] = pv_mfma(avf[ct][kcs], bp[kcs], accO[ct]);
    }

    lsum += __shfl_xor(lsum, 32);

    // ---- cross-wave combine: 4-slot LDS tree ----
#define ACC_STORE(SLOT)                                                        \
    do {                                                                       \
        _Pragma("unroll")                                                      \
        for (int ct = 0; ct < 2; ++ct)                                         \
            _Pragma("unroll")                                                  \
            for (int r = 0; r < 16; ++r)                                       \
                lds_acc[SLOT][ct * 32 + (r & 3) + 8 * (r >> 2) + 4 * hi][il] = accO[ct][r]; \
        if (hi == 0) lds_l[SLOT][il] = lsum;                                   \
    } while (0)
#define ACC_LOAD(SLOT)                                                         \
    do {                                                                       \
        _Pragma("unroll")                                                      \
        for (int ct = 0; ct < 2; ++ct)                                         \
            _Pragma("unroll")                                                  \
            for (int r = 0; r < 16; ++r)                                       \
                accO[ct][r] += lds_acc[SLOT][ct * 32 + (r & 3) + 8 * (r >> 2) + 4 * hi][il]; \
        lsum += lds_l[SLOT][il];                                               \
    } while (0)

    if (wave >= 4) ACC_STORE(wave - 4);
    __syncthreads();
    if (wave < 4) ACC_LOAD(wave);
    __syncthreads();
    if (wave >= 1 && wave < 4) ACC_STORE(wave - 1);
    __syncthreads();
    if (wave == 0) {
        ACC_LOAD(0); ACC_LOAD(1); ACC_LOAD(2);
        ACC_STORE(3);                        // totals -> slot 3
    }
    __syncthreads();
#undef ACC_STORE
#undef ACC_LOAD

    // ---- epilogue: out = gamma*O/l + x1 ----
    const float g = gamma[0];
    {
        const int c  = tid >> 3;          // 0..63
        const int i4 = (tid & 7) * 4;     // 0..28
        f32x4 o  = *(const f32x4*)&lds_acc[3][c][i4];
        f32x4 lt = *(const f32x4*)&lds_l[3][i4];
        const size_t idx = ((size_t)b * C + c) * N + ibase + i4;
        f32x4 xv = *(const f32x4*)(x1 + idx);
        f32x4 res;
#pragma unroll
        for (int e = 0; e < 4; ++e) res[e] = g * o[e] / lt[e] + xv[e];
        *(f32x4*)(out + idx) = res;
    }
}

// ---------------------------------------------------------------------------
extern "C" void kernel_launch(void* const* d_in, const int* in_sizes, int n_in,
                              void* d_out, int out_size, void* d_ws, size_t ws_size,
                              hipStream_t stream) {
    const float* x1    = (const float*)d_in[0];
    const float* x2    = (const float*)d_in[1];
    const float* wq    = (const float*)d_in[2];
    const float* bqv   = (const float*)d_in[3];
    const float* wk    = (const float*)d_in[4];
    const float* bkv   = (const float*)d_in[5];
    const float* wv    = (const float*)d_in[6];
    const float* bvv   = (const float*)d_in[7];
    const float* gamma = (const float*)d_in[8];
    float* out = (float*)d_out;

    __bf16* qws = (__bf16*)d_ws;                   // tiled Q, 2 MB
    __bf16* kws = qws + (size_t)4 * 128 * 2048;    // tiled K, 2 MB
    __bf16* vws = kws + (size_t)4 * 128 * 2048;    // tiled V, 2 MB

    qkv_kernel<<<256, 256, 0, stream>>>(x1, x2, wq, bqv, wk, bkv, wv, bvv, qws, kws, vws);
    attn_kernel<<<512, 512, 0, stream>>>(qws, kws, vws, x1, gamma, out);
}

// Round 5
// 104.593 us; speedup vs baseline: 2.3610x; 1.0304x over previous
//
#include <hip/hip_runtime.h>
#include <cstdint>
#include <cstddef>

// ---------------------------------------------------------------------------
// ChannelWiseCrossAttention: B=4, C=64, H=W=64, N=4096
// Workspace layouts are MFMA-fragment-major (wave-contiguous loads):
//   Q,K per (b, 32-row tile): [kc(4)][hi(2)][il(32)][e(8)]  (2048 elems)
//     element (row il, c = kc*16+hi*8+e)
//   V  per (b, 32-col tile):  [kcs(4)][hi(2)][c(64)][e(4)]  (2048 elems)
//     element (c, j = kcs*8+hi*4+e)
// attn: 256 blocks x 8 waves; block = 64 Q-rows (2 subtiles); wave = 1/8 of j.
//   Halves K/V L2 traffic vs 32-row blocks (each K/V tile feeds 2 S-tiles).
//   S^T = K Q^T (mfma_f32_32x32x16_bf16), p = exp2(S' - SHIFT) in-register,
//   O^T += V P^T (32x32x8; S^T C/D regs 4g..4g+3 are the B-frag).
//   8-wave partial (O,l) combine: 3-slot LDS tree + per-wave lsum array.
// ---------------------------------------------------------------------------

typedef __bf16 bf16x4 __attribute__((ext_vector_type(4)));
typedef __bf16 bf16x8 __attribute__((ext_vector_type(8)));
typedef float  f32x4  __attribute__((ext_vector_type(4)));
typedef float  f32x16 __attribute__((ext_vector_type(16)));
typedef short  s16x4  __attribute__((ext_vector_type(4)));

constexpr int C = 64;
constexpr int N = 4096;
constexpr float LOG2E = 1.44269504088896340736f;
constexpr float EXPSHIFT = 48.0f * 1.44269504088896340736f;  // ln-domain 48

static __device__ __forceinline__ f32x4 mfma16(bf16x8 a, bf16x8 b, f32x4 c) {
    return __builtin_amdgcn_mfma_f32_16x16x32_bf16(a, b, c, 0, 0, 0);
}
static __device__ __forceinline__ f32x16 mfma32(bf16x8 a, bf16x8 b, f32x16 c) {
    return __builtin_amdgcn_mfma_f32_32x32x16_bf16(a, b, c, 0, 0, 0);
}
// 32x32x8 bf16 (A/B = 4 bf16, k = 4*hi + j). Native if available, else
// zero-padded 32x32x16 (logical k at slot j in both operands).
static __device__ __forceinline__ f32x16 pv_mfma(bf16x4 a, bf16x4 b, f32x16 c) {
#if __has_builtin(__builtin_amdgcn_mfma_f32_32x32x8bf16_1k)
    union U { bf16x4 h; s16x4 s; };
    U ua; ua.h = a;
    U ub; ub.h = b;
    return __builtin_amdgcn_mfma_f32_32x32x8bf16_1k(ua.s, ub.s, c, 0, 0, 0);
#else
    const __bf16 z = (__bf16)0.0f;
    bf16x8 a8 = {a[0], a[1], a[2], a[3], z, z, z, z};
    bf16x8 b8 = {b[0], b[1], b[2], b[3], z, z, z, z};
    return __builtin_amdgcn_mfma_f32_32x32x16_bf16(a8, b8, c, 0, 0, 0);
#endif
}
static __device__ __forceinline__ float fast_exp2(float x) {
#if __has_builtin(__builtin_amdgcn_exp2f)
    return __builtin_amdgcn_exp2f(x);
#else
    return exp2f(x);
#endif
}

// ---------------------------------------------------------------------------
// QKV conv (unchanged from round 4). grid = 256 x 256 thr.
// ---------------------------------------------------------------------------
__global__ __launch_bounds__(256) void qkv_kernel(
    const float* __restrict__ x1, const float* __restrict__ x2,
    const float* __restrict__ wq, const float* __restrict__ bq,
    const float* __restrict__ wk, const float* __restrict__ bk,
    const float* __restrict__ wv, const float* __restrict__ bv,
    __bf16* __restrict__ qo, __bf16* __restrict__ ko, __bf16* __restrict__ vo)
{
    __shared__ __bf16 wl[3][64][72];

    const int tid   = threadIdx.x;
    const int b     = blockIdx.x >> 6;
    const int nbase = (blockIdx.x & 63) * 64;

    {
        const float* wp[3] = {wq, wk, wv};
#pragma unroll
        for (int m = 0; m < 3; ++m)
#pragma unroll
            for (int i = 0; i < 4; ++i) {
                int idx = i * 256 + tid;
                int row = idx >> 4, c4 = (idx & 15) * 4;
                float4 a = *(const float4*)(wp[m] + row * 64 + c4);
                bf16x4 h = {(__bf16)a.x, (__bf16)a.y, (__bf16)a.z, (__bf16)a.w};
                *(bf16x4*)&wl[m][row][c4] = h;
            }
    }
    __syncthreads();

    const int wave = tid >> 6, lane = tid & 63;
    const int l = lane & 15, qd = lane >> 4;
    const int p = nbase + wave * 16 + l;

    const float* x1b = x1 + (size_t)b * C * N + p;
    const float* x2b = x2 + (size_t)b * C * N + p;
    bf16x8 ax1[2], ax2[2];
#pragma unroll
    for (int ks = 0; ks < 2; ++ks)
#pragma unroll
        for (int j = 0; j < 8; ++j) {
            int c = ks * 32 + qd * 8 + j;
            ax1[ks][j] = (__bf16)x1b[(size_t)c * N];
            ax2[ks][j] = (__bf16)x2b[(size_t)c * N];
        }

    const size_t tb = ((size_t)b * 128 + (nbase >> 5) + (wave >> 1)) * 2048;

#pragma unroll
    for (int ot = 0; ot < 4; ++ot) {
        const float bqv = bq[ot * 16 + l];
        const float bkv = bk[ot * 16 + l];
        f32x4 aq = {bqv, bqv, bqv, bqv};
        f32x4 ak = {bkv, bkv, bkv, bkv};
#pragma unroll
        for (int ks = 0; ks < 2; ++ks) {
            bf16x8 bwq = *(const bf16x8*)&wl[0][ot * 16 + l][ks * 32 + qd * 8];
            bf16x8 bwk = *(const bf16x8*)&wl[1][ot * 16 + l][ks * 32 + qd * 8];
            aq = mfma16(ax1[ks], bwq, aq);
            ak = mfma16(ax2[ks], bwk, ak);
        }
#pragma unroll
        for (int r = 0; r < 4; ++r) {
            int p32 = (wave & 1) * 16 + qd * 4 + r;
            size_t idx = tb + ot * 512 + (l >> 3) * 256 + p32 * 8 + (l & 7);
            qo[idx] = (__bf16)(aq[r] * LOG2E);
            ko[idx] = (__bf16)ak[r];
        }
    }

    const int kcs = ((wave & 1) * 16 + l) >> 3;
    const int vhi = (l >> 2) & 1;
#pragma unroll
    for (int ct = 0; ct < 4; ++ct) {
        f32x4 av;
#pragma unroll
        for (int r = 0; r < 4; ++r) av[r] = bv[ct * 16 + qd * 4 + r];
#pragma unroll
        for (int ks = 0; ks < 2; ++ks) {
            bf16x8 awv = *(const bf16x8*)&wl[2][ct * 16 + l][ks * 32 + qd * 8];
            av = mfma16(awv, ax2[ks], av);
        }
#pragma unroll
        for (int r = 0; r < 4; ++r) {
            int o = ct * 16 + qd * 4 + r;
            vo[tb + kcs * 512 + vhi * 256 + o * 4 + (l & 3)] = (__bf16)av[r];
        }
    }
}

// ---------------------------------------------------------------------------
// Attention. grid = 256 blocks x 512 thr. Block = (b, 64-row Q-tile = 2
// subtiles); wave w owns j-tiles [w*16, w*16+16), reusing each K/V tile for
// both Q-subtiles. XCD swizzle: batch per XCD pair.
// 32x32x16: A/B 8 elems k=(lane>>5)*8+j; C/D row=(r&3)+8*(r>>2)+4*hi, col=il.
// ---------------------------------------------------------------------------
__global__ __launch_bounds__(512, 2) void attn_kernel(
    const __bf16* __restrict__ qg, const __bf16* __restrict__ kg,
    const __bf16* __restrict__ vg, const float* __restrict__ x1,
    const float* __restrict__ gamma, float* __restrict__ out)
{
    __shared__ float lds_acc[3][64][64];   // 3 combine slots, 48 KB, [c][i]
    __shared__ float lds_l[8][64];         // per-wave lsum partials, [w][i]

    const int bid = blockIdx.x;
    const int xcd = bid & 7;
    const int b   = xcd >> 1;
    const int rt  = ((bid >> 3) << 1) | (xcd & 1);   // 0..63 (64-row tile)
    const int ibase = rt * 64;

    const int tid  = threadIdx.x;
    const int wave = tid >> 6, lane = tid & 63;
    const int il = lane & 31, hi = lane >> 5;

    const __bf16* qt = qg + ((size_t)b * 128 + rt * 2) * 2048;
    const __bf16* kt = kg + (size_t)b * 128 * 2048 + (size_t)(wave * 16) * 2048;
    const __bf16* vt = vg + (size_t)b * 128 * 2048 + (size_t)(wave * 16) * 2048;

    // Q B-frags for both 32-row subtiles: 1 KB contiguous per load
    bf16x8 bqf[2][4];
#pragma unroll
    for (int qs = 0; qs < 2; ++qs)
#pragma unroll
        for (int kc = 0; kc < 4; ++kc)
            bqf[qs][kc] = *(const bf16x8*)(qt + qs * 2048 + kc * 512 + lane * 8);

    f32x16 accO[4];   // [qs*2 + ct]
#pragma unroll
    for (int a = 0; a < 4; ++a)
#pragma unroll
        for (int r = 0; r < 16; ++r) accO[a][r] = 0.f;
    float lsum[2] = {0.f, 0.f};

    bf16x8 akf[2][4];   // K frags, double-buffered
    bf16x4 avf[2][4];   // V frags [ct][kcs]

#pragma unroll
    for (int kc = 0; kc < 4; ++kc)
        akf[0][kc] = *(const bf16x8*)(kt + kc * 512 + lane * 8);

#pragma unroll 4
    for (int t = 0; t < 16; ++t) {
        const int cur = t & 1;
        if (t < 15) {
#pragma unroll
            for (int kc = 0; kc < 4; ++kc)
                akf[cur ^ 1][kc] = *(const bf16x8*)(kt + (size_t)(t + 1) * 2048 + kc * 512 + lane * 8);
        }
#pragma unroll
        for (int ct = 0; ct < 2; ++ct)
#pragma unroll
            for (int kcs = 0; kcs < 4; ++kcs)
                avf[ct][kcs] = *(const bf16x4*)(vt + (size_t)t * 2048 + kcs * 512 + hi * 256 + ct * 128 + il * 4);

#pragma unroll
        for (int qs = 0; qs < 2; ++qs) {
            // S^T = K Q^T for this Q-subtile
            f32x16 st;
#pragma unroll
            for (int r = 0; r < 16; ++r) st[r] = 0.f;
#pragma unroll
            for (int kc = 0; kc < 4; ++kc) st = mfma32(akf[cur][kc], bqf[qs][kc], st);

            // p = exp2(S' - SHIFT); regs 4g..4g+3 = B-frag of PV k-chunk g
            bf16x4 bp[4];
            float ls = 0.f;
#pragma unroll
            for (int r = 0; r < 16; ++r) {
                float pv = fast_exp2(st[r] - EXPSHIFT);
                ls += pv;
                bp[r >> 2][r & 3] = (__bf16)pv;
            }
            lsum[qs] += ls;

            // O^T += V P^T
#pragma unroll
            for (int ct = 0; ct < 2; ++ct)
#pragma unroll
                for (int kcs = 0; kcs < 4; ++kcs)
                    accO[qs * 2 + ct] = pv_mfma(avf[ct][kcs], bp[kcs], accO[qs * 2 + ct]);
        }
    }

    // per-lane lsum -> per-column(i) sum within wave (pair hi halves)
#pragma unroll
    for (int qs = 0; qs < 2; ++qs) lsum[qs] += __shfl_xor(lsum[qs], 32);
    if (hi == 0) {
        lds_l[wave][il]      = lsum[0];
        lds_l[wave][32 + il] = lsum[1];
    }

    // ---- cross-wave combine: 3-slot LDS tree ----
    // accO element (qs,ct,r) -> c = ct*32+(r&3)+8*(r>>2)+4*hi, i = qs*32+il
    // [c][i] scalar stores: bank = i%32 -> conflict-free (2-way across hi).
#define ACC_STORE(SLOT)                                                        \
    do {                                                                       \
        _Pragma("unroll")                                                      \
        for (int qs = 0; qs < 2; ++qs)                                         \
            _Pragma("unroll")                                                  \
            for (int ct = 0; ct < 2; ++ct)                                     \
                _Pragma("unroll")                                              \
                for (int r = 0; r < 16; ++r)                                   \
                    lds_acc[SLOT][ct * 32 + (r & 3) + 8 * (r >> 2) + 4 * hi][qs * 32 + il] = accO[qs * 2 + ct][r]; \
    } while (0)
#define ACC_LOAD(SLOT)                                                         \
    do {                                                                       \
        _Pragma("unroll")                                                      \
        for (int qs = 0; qs < 2; ++qs)                                         \
            _Pragma("unroll")                                                  \
            for (int ct = 0; ct < 2; ++ct)                                     \
                _Pragma("unroll")                                              \
                for (int r = 0; r < 16; ++r)                                   \
                    accO[qs * 2 + ct][r] += lds_acc[SLOT][ct * 32 + (r & 3) + 8 * (r >> 2) + 4 * hi][qs * 32 + il]; \
    } while (0)

    if (wave >= 5) ACC_STORE(wave - 5);                 // w5->0, w6->1, w7->2
    __syncthreads();
    if (wave >= 1 && wave <= 3) ACC_LOAD(wave - 1);     // w1+=w5, w2+=w6, w3+=w7
    __syncthreads();
    if (wave >= 2 && wave <= 4) ACC_STORE(wave - 2);    // w2->0, w3->1, w4->2
    __syncthreads();
    if (wave <= 1) ACC_LOAD(wave);                      // w0+=(w2+w6), w1+=(w3+w7)
    if (wave == 0) ACC_LOAD(2);                         // w0+=w4
    __syncthreads();
    if (wave == 1) ACC_STORE(0);                        // (w1+w5+w3+w7) -> s0
    __syncthreads();
    if (wave == 0) { ACC_LOAD(0); ACC_STORE(0); }       // total -> s0
    __syncthreads();
#undef ACC_STORE
#undef ACC_LOAD

    // ---- epilogue: out = gamma*O/l + x1 ----
    const float g = gamma[0];
    {
        const int c  = tid >> 3;           // 0..63
        const int i8 = (tid & 7) * 8;      // 0..56
        float lv[8];
#pragma unroll
        for (int e = 0; e < 8; ++e) {
            float s = 0.f;
#pragma unroll
            for (int w = 0; w < 8; ++w) s += lds_l[w][i8 + e];
            lv[e] = s;
        }
        const size_t idx = ((size_t)b * C + c) * N + ibase + i8;
        f32x4 o0 = *(const f32x4*)&lds_acc[0][c][i8];
        f32x4 o1 = *(const f32x4*)&lds_acc[0][c][i8 + 4];
        f32x4 x0 = *(const f32x4*)(x1 + idx);
        f32x4 x4 = *(const f32x4*)(x1 + idx + 4);
        f32x4 r0, r1;
#pragma unroll
        for (int e = 0; e < 4; ++e) {
            r0[e] = g * o0[e] / lv[e] + x0[e];
            r1[e] = g * o1[e] / lv[4 + e] + x4[e];
        }
        *(f32x4*)(out + idx) = r0;
        *(f32x4*)(out + idx + 4) = r1;
    }
}

// ---------------------------------------------------------------------------
extern "C" void kernel_launch(void* const* d_in, const int* in_sizes, int n_in,
                              void* d_out, int out_size, void* d_ws, size_t ws_size,
                              hipStream_t stream) {
    const float* x1    = (const float*)d_in[0];
    const float* x2    = (const float*)d_in[1];
    const float* wq    = (const float*)d_in[2];
    const float* bqv   = (const float*)d_in[3];
    const float* wk    = (const float*)d_in[4];
    const float* bkv   = (const float*)d_in[5];
    const float* wv    = (const float*)d_in[6];
    const float* bvv   = (const float*)d_in[7];
    const float* gamma = (const float*)d_in[8];
    float* out = (float*)d_out;

    __bf16* qws = (__bf16*)d_ws;                   // tiled Q, 2 MB
    __bf16* kws = qws + (size_t)4 * 128 * 2048;    // tiled K, 2 MB
    __bf16* vws = kws + (size_t)4 * 128 * 2048;    // tiled V, 2 MB

    qkv_kernel<<<256, 256, 0, stream>>>(x1, x2, wq, bqv, wk, bkv, wv, bvv, qws, kws, vws);
    attn_kernel<<<256, 512, 0, stream>>>(qws, kws, vws, x1, gamma, out);
}